// Round 6
// baseline (581.931 us; speedup 1.0000x reference)
//
#include <hip/hip_runtime.h>
#include <cfloat>

#define T_TOTAL 32768   // 32*32*32 spatial positions
#define DIM 64          // embedding dim
#define KCODES 1024     // num embeddings

typedef float f32x2 __attribute__((ext_vector_type(2)));

// d_out flat layout (fp32), reference return order:
//   quantized_out [32,64,32,32] = 2097152 | loss | perplexity
//   encodings [32768,1024] | distances [32768,1024]
static constexpr long long OFF_Q    = 0;
static constexpr long long OFF_LOSS = 2097152;
static constexpr long long OFF_PERP = 2097153;
static constexpr long long OFF_ENC  = 2097154;                 // 8B aligned only
static constexpr long long OFF_DIST = 2097154LL + 33554432LL;  // 8B aligned only

// Scratch carved out of the ENC region (written by prep, read by K1, fully
// overwritten by K3 which runs strictly after K1 on the same stream):
//   xTg  = enc[0 .. 2097152)            row-major x [32768][64]
//   xxg  = enc[2097152 .. 2129920)      ||x_row||^2 [32768]
// Per-(row,slice) argmin partials live in the Q region, n-planes 0..7 of each
// row's own (b,jd) column — owned exclusively by the K3 block that later
// overwrites them (no cross-block hazard).
static constexpr long long OFF_XTG = OFF_ENC;
static constexpr long long OFF_XX  = OFF_ENC + 2097152LL;

// ws: [0,4096) int counts[1024]; [4096,8192) float ww[1024]; [8192,8196) lossSum

// ---------------------------------------------------------------------------
// Prep: blocks 0..255 -> ww ; blocks 256..383 -> xTg transpose + xx.
__global__ __launch_bounds__(256) void vq_prep_kernel(const float* __restrict__ W,
                                                      const float* __restrict__ lat,
                                                      float* __restrict__ ww,
                                                      float* __restrict__ out) {
    const int tid = threadIdx.x;
    if (blockIdx.x < 256) {
        const int lane = tid & 63;
        const int code = blockIdx.x * 4 + (tid >> 6);
        float v = W[code * DIM + lane];
        float s = v * v;
        #pragma unroll
        for (int off = 32; off > 0; off >>= 1)
            s += __shfl_down(s, off, 64);
        if (lane == 0) ww[code] = s;
        return;
    }
    // transpose: block bi covers batch b, jd columns jd0..jd0+255
    __shared__ float tile[256 * 17];   // [jd_local][n_rel], stride 17 kills conflicts
    const int bi  = blockIdx.x - 256;  // 0..127
    const int b   = bi >> 2;
    const int jd0 = (bi & 3) * 256;
    float* __restrict__ xTg = out + OFF_XTG;
    float* __restrict__ xxg = out + OFF_XX;
    float sp = 0.f;
    for (int g = 0; g < 4; ++g) {
        if (g) __syncthreads();
        #pragma unroll
        for (int it = 0; it < 16; ++it) {        // n = g*16+it, jd = jd0+tid (coalesced)
            float v = lat[(long long)b * 65536 + (g * 16 + it) * 1024 + jd0 + tid];
            tile[tid * 17 + it] = v;
            sp = fmaf(v, v, sp);                 // ascending-n chain per jd column
        }
        __syncthreads();
        #pragma unroll
        for (int it = 0; it < 16; ++it) {        // write xTg[row][n], n fastest
            int rl = it * 16 + (tid >> 4);
            int n  = tid & 15;
            xTg[(long long)(b * 1024 + jd0 + rl) * 64 + g * 16 + n] = tile[rl * 17 + n];
        }
    }
    xxg[b * 1024 + jd0 + tid] = sp;
}

// ---------------------------------------------------------------------------
// K1: distance GEMM + per-(row,slice) argmin partials.
// 2048 blocks (4 code-slices x 512 row-tiles of 64 rows) x 256 threads.
// Lane owns code = s*256 + wave*64 + lane: its 64 W-values live in VGPRs.
// Row is wave-uniform: x row + xx come from scalar loads (SGPR operands).
// Hot loop has NO vector-memory loads -> nontemporal dist stores never stall.
__global__ __launch_bounds__(256, 4) void vq_dist_kernel(const float* __restrict__ W,
                                                         const float* __restrict__ ww,
                                                         float* __restrict__ out) {
    __shared__ float pv[64 * 4];
    __shared__ int   pi[64 * 4];

    const int tid  = threadIdx.x;
    const int lane = tid & 63;
    const int w    = tid >> 6;
    const int s    = blockIdx.x & 3;
    const int rowBase = (blockIdx.x >> 2) * 64;
    const int code = s * 256 + w * 64 + lane;

    // codebook fragment -> registers (one-time, L2-served)
    float4 bb[16];
    const float4* wp4 = (const float4*)(W + code * DIM);
    #pragma unroll
    for (int i = 0; i < 16; ++i) bb[i] = wp4[i];
    const float wwv = ww[code];

    const float* __restrict__ xTg = out + OFF_XTG;
    const float* __restrict__ xxg = out + OFF_XX;
    float* __restrict__ dist = out + OFF_DIST;

    for (int r = 0; r < 64; ++r) {
        const int row = rowBase + r;
        const float* xr = xTg + (long long)row * 64;   // uniform -> s_load
        float acc = 0.f;
        #pragma unroll
        for (int i = 0; i < 16; ++i) {
            acc = fmaf(xr[i * 4 + 0], bb[i].x, acc);
            acc = fmaf(xr[i * 4 + 1], bb[i].y, acc);
            acc = fmaf(xr[i * 4 + 2], bb[i].z, acc);
            acc = fmaf(xr[i * 4 + 3], bb[i].w, acc);
        }
        const float d = (xxg[row] + wwv) - 2.f * acc;
        // wave-wide min + lowest-lane-of-min (== np first-occurrence)
        float m = d;
        #pragma unroll
        for (int off = 1; off < 64; off <<= 1)
            m = fminf(m, __shfl_xor(m, off, 64));
        unsigned long long msk = __ballot(d == m);
        if (lane == 0) {
            int ml = (int)__builtin_ctzll(msk);
            pv[r * 4 + w] = m;
            pi[r * 4 + w] = s * 256 + w * 64 + ml;
        }
        __builtin_nontemporal_store(d, &dist[(long long)row * KCODES + code]);
    }
    __syncthreads();

    // combine the 4 wave partials; stash into this row's own q n-planes 0..7
    if (tid < 64) {
        float best = pv[tid * 4];
        int   bi   = pi[tid * 4];
        #pragma unroll
        for (int q = 1; q < 4; ++q) {
            float v  = pv[tid * 4 + q];
            int   i2 = pi[tid * 4 + q];
            if (v < best || (v == best && i2 < bi)) { best = v; bi = i2; }
        }
        const int row = rowBase + tid;
        const long long qb = (long long)(row >> 10) * 65536 + (row & 1023);
        out[OFF_Q + qb + (long long)(s * 2)     * 1024] = best;
        out[OFF_Q + qb + (long long)(s * 2 + 1) * 1024] = __int_as_float(bi);
    }
}

// ---------------------------------------------------------------------------
// K3: epilogue. 512 blocks x 64 rows: final argmin across 4 slices, counts,
// gather -> quantized + loss, one-hot encodings. Overwrites all scratch.
__global__ __launch_bounds__(256) void vq_epi_kernel(const float* __restrict__ lat,
                                                     const float* __restrict__ W,
                                                     float* __restrict__ out,
                                                     int* __restrict__ counts,
                                                     float* __restrict__ lossSum) {
    __shared__ float xT[64 * 64];      // [n][tl] 16 KB
    __shared__ float qS[64 * 65];      // gathered codes, +1 pad
    __shared__ int   selS[64];

    const int tid = threadIdx.x;
    const int t0  = blockIdx.x * 64;
    const long long base = (long long)(t0 >> 10) * 65536 + (long long)(t0 & 1023);

    // final per-row argmin from slice partials (this block's own q n-planes)
    if (tid < 64) {
        const long long qb = base + tid;
        float best = out[OFF_Q + qb];
        int   bi   = __float_as_int(out[OFF_Q + qb + 1024]);
        #pragma unroll
        for (int s = 1; s < 4; ++s) {
            float v  = out[OFF_Q + qb + (long long)(s * 2) * 1024];
            int   i2 = __float_as_int(out[OFF_Q + qb + (long long)(s * 2 + 1) * 1024]);
            if (v < best || (v == best && i2 < bi)) { best = v; bi = i2; }
        }
        selS[tid] = bi;
        atomicAdd(&counts[bi], 1);
    }
    // stage x tile (all 256 threads, coalesced)
    #pragma unroll
    for (int i = 0; i < 16; ++i) {
        int e  = i * 256 + tid;
        int n  = e >> 6;
        int tl = e & 63;
        xT[n * 64 + tl] = lat[base + (long long)n * 1024 + tl];
    }
    __syncthreads();

    // gather selected codebook rows (coalesced, stride-65)
    #pragma unroll
    for (int i = 0; i < 16; ++i) {
        int e   = i * 256 + tid;
        int row = e >> 6;
        int n   = e & 63;
        qS[row * 65 + n] = W[selS[row] * DIM + n];
    }
    __syncthreads();

    // quantized_out (dense float4, overwrites partial planes) + loss partial
    float ls = 0.f;
    #pragma unroll
    for (int i = 0; i < 4; ++i) {
        int e2  = i * 256 + tid;       // [0,1024) float4 slots
        int n   = e2 >> 4;
        int tl0 = (e2 & 15) * 4;
        float q0 = qS[(tl0 + 0) * 65 + n];
        float q1 = qS[(tl0 + 1) * 65 + n];
        float q2 = qS[(tl0 + 2) * 65 + n];
        float q3 = qS[(tl0 + 3) * 65 + n];
        float x0 = xT[n * 64 + tl0 + 0];
        float x1 = xT[n * 64 + tl0 + 1];
        float x2 = xT[n * 64 + tl0 + 2];
        float x3 = xT[n * 64 + tl0 + 3];
        *(float4*)&out[OFF_Q + base + (long long)n * 1024 + tl0] = make_float4(q0, q1, q2, q3);
        float e0 = q0 - x0; ls = fmaf(e0, e0, ls);
        float e1 = q1 - x1; ls = fmaf(e1, e1, ls);
        float e2d = q2 - x2; ls = fmaf(e2d, e2d, ls);
        float e3 = q3 - x3; ls = fmaf(e3, e3, ls);
    }
    #pragma unroll
    for (int off = 32; off > 0; off >>= 1)
        ls += __shfl_down(ls, off, 64);
    if ((tid & 63) == 0) atomicAdd(lossSum, ls);

    // one-hot encodings (overwrites xTg/xx scratch region too)
    float* __restrict__ enc = out + OFF_ENC;
    #pragma unroll 4
    for (int i = 0; i < 128; ++i) {
        int e2  = i * 256 + tid;       // [0,32768) float2 slots
        int row = e2 >> 9;
        int k2  = (e2 & 511) * 2;
        int sel = selS[row];
        f32x2 v;
        v.x = (k2     == sel) ? 1.f : 0.f;
        v.y = (k2 + 1 == sel) ? 1.f : 0.f;
        __builtin_nontemporal_store(v, (f32x2*)&enc[(long long)(t0 + row) * KCODES + k2]);
    }
}

// ---------------------------------------------------------------------------
__global__ __launch_bounds__(1024) void vq_finalize_kernel(const int* __restrict__ counts,
                                                           const float* __restrict__ lossSum,
                                                           float* __restrict__ out) {
    __shared__ float red[16];
    const int tid = threadIdx.x;
    float p = (float)counts[tid] * (1.0f / 32768.0f);
    float term = p * logf(p + 1e-10f);
    #pragma unroll
    for (int off = 32; off > 0; off >>= 1)
        term += __shfl_down(term, off, 64);
    if ((tid & 63) == 0) red[tid >> 6] = term;
    __syncthreads();
    if (tid == 0) {
        float s = 0.f;
        #pragma unroll
        for (int i = 0; i < 16; ++i) s += red[i];
        out[OFF_PERP] = expf(-s);
        out[OFF_LOSS] = 0.25f * lossSum[0] * (1.0f / 2097152.0f);
    }
}

// ---------------------------------------------------------------------------
extern "C" void kernel_launch(void* const* d_in, const int* in_sizes, int n_in,
                              void* d_out, int out_size, void* d_ws, size_t ws_size,
                              hipStream_t stream) {
    (void)in_sizes; (void)n_in; (void)out_size; (void)ws_size;
    const float* lat = (const float*)d_in[0];   // [32,64,32,32]
    const float* W   = (const float*)d_in[1];   // [1024,64]
    float* out = (float*)d_out;

    int*   counts  = (int*)d_ws;
    float* ww      = (float*)((char*)d_ws + 4096);
    float* lossSum = (float*)((char*)d_ws + 8192);

    (void)hipMemsetAsync(d_ws, 0, 8192 + 16, stream);

    vq_prep_kernel<<<384, 256, 0, stream>>>(W, lat, ww, out);
    vq_dist_kernel<<<2048, 256, 0, stream>>>(W, ww, out);
    vq_epi_kernel<<<512, 256, 0, stream>>>(lat, W, out, counts, lossSum);
    vq_finalize_kernel<<<1, 1024, 0, stream>>>(counts, lossSum, out);
}